// Round 4
// baseline (605.638 us; speedup 1.0000x reference)
//
#include <hip/hip_runtime.h>

// GAE: h1 = relu(spmm(X@W1)); h2 = relu(spmm(h1@W2)); Z = spmm(h2@W3);
// A = sigmoid(Z @ Z^T).  Outputs: [A (12288x12288), Z (12288x16)] fp32, concat.
//
// Pipeline (7 dispatches + 1 tiny memset):
//   memset(cnt) -> [csr_count || gemm1] -> csr_scan -> csr_scatter
//   -> spmm+relu+@W2 (fused) -> spmm+relu+@W3 (fused) -> spmm16 -> decode
// CSR scratch lives in the tail of A (decode overwrites it last).

constexpr int NN = 12288;   // nodes
constexpr int NE = 393216;  // edges
constexpr int KD = 1433;    // input dim

typedef float f32x4 __attribute__((ext_vector_type(4)));

// ---------------- fused: csr_count || gemm1 ----------------
// blocks [0, NE/256): histogram er into cnt.
// blocks [NE/256, NE/256 + NN*32/256): X[NN,1433] @ W1[1433,32] -> out.
// X rows are 4B-aligned only (KD%4==1): per-row head/tail, float4 body.
__global__ __launch_bounds__(256) void k_count_gemm1(const int* __restrict__ er,
                                                     int* __restrict__ cnt,
                                                     const float* __restrict__ X,
                                                     const float* __restrict__ W,
                                                     float* __restrict__ out) {
    if (blockIdx.x < NE / 256) {
        int e = blockIdx.x * 256 + threadIdx.x;
        atomicAdd(&cnt[er[e]], 1);
        return;
    }
    int tid = (blockIdx.x - NE / 256) * 256 + threadIdx.x;
    int row = tid >> 5, col = tid & 31;
    const float* xr = X + (size_t)row * KD;
    float acc = 0.f;
    int head = (4 - (row & 3)) & 3;          // elements until 16B boundary
    for (int k = 0; k < head; ++k) acc += xr[k] * W[k * 32 + col];
    int nv = (KD - head) >> 2;               // float4 chunks
    const f32x4* x4 = (const f32x4*)(xr + head);
#pragma unroll 2
    for (int q = 0; q < nv; ++q) {
        f32x4 a = x4[q];
        int k = head + q * 4;
        acc += a[0] * W[(k + 0) * 32 + col];
        acc += a[1] * W[(k + 1) * 32 + col];
        acc += a[2] * W[(k + 2) * 32 + col];
        acc += a[3] * W[(k + 3) * 32 + col];
    }
    for (int k = head + nv * 4; k < KD; ++k) acc += xr[k] * W[k * 32 + col];
    out[(size_t)row * 32 + col] = acc;
}

// ---------------- CSR scan: one block, 1024 threads, 12 rows each ----------------
__global__ __launch_bounds__(1024) void csr_scan(const int* __restrict__ cnt,
                                                 int* __restrict__ ptr,
                                                 int* __restrict__ pos) {
    __shared__ int s[1024];
    int t = threadIdx.x;
    int base = t * 12;
    int loc[12];
    int sum = 0;
#pragma unroll
    for (int i = 0; i < 12; ++i) { loc[i] = sum; sum += cnt[base + i]; }
    s[t] = sum;
    __syncthreads();
    for (int off = 1; off < 1024; off <<= 1) {
        int v = (t >= off) ? s[t - off] : 0;
        __syncthreads();
        s[t] += v;
        __syncthreads();
    }
    int excl = (t == 0) ? 0 : s[t - 1];
#pragma unroll
    for (int i = 0; i < 12; ++i) {
        ptr[base + i] = excl + loc[i];
        pos[base + i] = excl + loc[i];
    }
    if (t == 0) ptr[NN] = NE;
}

__global__ __launch_bounds__(256) void csr_scatter(const float* __restrict__ ev,
                                                   const int* __restrict__ er,
                                                   const int* __restrict__ ec,
                                                   int* __restrict__ pos,
                                                   int* __restrict__ ecol,
                                                   float* __restrict__ eval) {
    int e = blockIdx.x * 256 + threadIdx.x;
    int r = er[e];
    int p = atomicAdd(&pos[r], 1);
    ecol[p] = ec[e];
    eval[p] = ev[e];
}

// ---------------- fused SpMM + relu + dense GEMM ----------------
// in [NN,32] pre-activation. Lane c of a half-wave row-group gathers chan c,
// relu in-register, then out[r,co] = sum_k relu(h[r,k]) * Wm[k,co] via __shfl
// across the half-wave (which holds the full 32-chan row) x preloaded W col.
template <int CO>
__global__ __launch_bounds__(256) void spmm_gemm(const float* __restrict__ in,
                                                 const float* __restrict__ Wm,
                                                 float* __restrict__ out,
                                                 const int* __restrict__ ptr,
                                                 const int* __restrict__ ecol,
                                                 const float* __restrict__ eval) {
    int tid = blockIdx.x * 256 + threadIdx.x;
    int r = tid >> 5, c = tid & 31;
    int lane = threadIdx.x & 63;
    int co = c & (CO - 1);
    float wcol[32];
#pragma unroll
    for (int k = 0; k < 32; ++k) wcol[k] = Wm[k * CO + co];
    int b = ptr[r], e = ptr[r + 1];
    float acc = 0.f;
#pragma unroll 2
    for (int i = b; i < e; ++i)
        acc += eval[i] * in[(size_t)ecol[i] * 32 + c];
    float h = fmaxf(acc, 0.f);
    float o = 0.f;
#pragma unroll
    for (int k = 0; k < 32; ++k) {
        float hk = __shfl(h, (lane & 32) + k);
        o += hk * wcol[k];
    }
    if (c < CO) out[(size_t)r * CO + co] = o;
}

// ---------------- plain SpMM gather, width 16 (final Z) ----------------
__global__ __launch_bounds__(256) void spmm16(const float* __restrict__ in,
                                              float* __restrict__ out,
                                              const int* __restrict__ ptr,
                                              const int* __restrict__ ecol,
                                              const float* __restrict__ eval) {
    int tid = blockIdx.x * 256 + threadIdx.x;
    int r = tid >> 4, c = tid & 15;
    int b = ptr[r], e = ptr[r + 1];
    float acc = 0.f;
#pragma unroll 2
    for (int i = b; i < e; ++i)
        acc += eval[i] * in[(size_t)ecol[i] * 16 + c];
    out[(size_t)r * 16 + c] = acc;
}

// ---------------- decode: A[i,j] = sigmoid(dot16(Z[i], Z[j])) ----------------
// 64x64 tile / 256 threads; 4 rows x 4 cols per thread. No LDS: each Z row is
// exactly one 64B line -> global float4 reads are L1-served. nt float4 stores.
__global__ __launch_bounds__(256) void decode(const float* __restrict__ Z,
                                              float* __restrict__ A) {
    int bi = blockIdx.y, bj = blockIdx.x;
    int tid = threadIdx.x;
    int jq = tid & 15;   // col group (4 cols)
    int i0 = tid >> 4;   // row phase 0..15
    const f32x4* Zv = (const f32x4*)Z;
    f32x4 zj[4][4];
#pragma unroll
    for (int jj = 0; jj < 4; ++jj) {
        int rowj = bj * 64 + jq * 4 + jj;
#pragma unroll
        for (int q = 0; q < 4; ++q) zj[jj][q] = Zv[rowj * 4 + q];
    }
#pragma unroll
    for (int ii = 0; ii < 4; ++ii) {
        int i = bi * 64 + ii * 16 + i0;
        f32x4 zi[4];
#pragma unroll
        for (int q = 0; q < 4; ++q) zi[q] = Zv[i * 4 + q];
        f32x4 o;
#pragma unroll
        for (int jj = 0; jj < 4; ++jj) {
            float dot = 0.f;
#pragma unroll
            for (int q = 0; q < 4; ++q)
#pragma unroll
                for (int m = 0; m < 4; ++m) dot += zi[q][m] * zj[jj][q][m];
            float e = __expf(-dot);
            o[jj] = __fdividef(1.0f, 1.0f + e);
        }
        f32x4* dst = (f32x4*)&A[(size_t)i * NN + bj * 64 + jq * 4];
        __builtin_nontemporal_store(o, dst);
    }
}

extern "C" void kernel_launch(void* const* d_in, const int* in_sizes, int n_in,
                              void* d_out, int out_size, void* d_ws, size_t ws_size,
                              hipStream_t stream) {
    const float* X  = (const float*)d_in[0];
    const float* W1 = (const float*)d_in[1];
    const float* W2 = (const float*)d_in[2];
    const float* W3 = (const float*)d_in[3];
    const float* ev = (const float*)d_in[4];
    const int*   er = (const int*)d_in[5];
    const int*   ec = (const int*)d_in[6];

    float* A = (float*)d_out;                 // [NN, NN]
    float* Z = A + (size_t)NN * NN;           // [NN, 16]

    float* t1 = (float*)d_ws;                 // [NN, 32]  X@W1
    float* t2 = t1 + (size_t)NN * 32;         // [NN, 32]  relu(spmm(t1))@W2
    float* t3 = t2 + (size_t)NN * 32;         // [NN, 16]  relu(spmm(t2))@W3

    // CSR scratch in the tail of A (decode overwrites it last). ~3.3MB at
    // 560MB offset; A is 604MB.
    int*   cnt  = (int*)(A + (size_t)140000000);
    int*   ptr  = cnt + NN;          // NN+1
    int*   pos  = ptr + NN + 1;      // NN
    int*   ecol = pos + NN;          // NE
    float* eval = (float*)(ecol + NE);  // NE

    (void)hipMemsetAsync(cnt, 0, NN * sizeof(int), stream);

    // count || gemm1 (independent, fused into one dispatch)
    k_count_gemm1<<<NE / 256 + NN * 32 / 256, 256, 0, stream>>>(er, cnt, X, W1, t1);
    csr_scan<<<1, 1024, 0, stream>>>(cnt, ptr, pos);
    csr_scatter<<<NE / 256, 256, 0, stream>>>(ev, er, ec, pos, ecol, eval);

    // t2 = relu(spmm(t1)) @ W2
    spmm_gemm<32><<<NN * 32 / 256, 256, 0, stream>>>(t1, W2, t2, ptr, ecol, eval);
    // t3 = relu(spmm(t2)) @ W3
    spmm_gemm<16><<<NN * 32 / 256, 256, 0, stream>>>(t2, W3, t3, ptr, ecol, eval);
    // Z = spmm(t3)
    spmm16<<<NN * 16 / 256, 256, 0, stream>>>(t3, Z, ptr, ecol, eval);

    // A = sigmoid(Z @ Z^T)
    dim3 g(NN / 64, NN / 64);
    decode<<<g, 256, 0, stream>>>(Z, A);
}

// Round 5
// 406.042 us; speedup vs baseline: 1.4916x; 1.4916x over previous
//
#include <hip/hip_runtime.h>

// GAE: h1 = relu(spmm(X@W1)); h2 = relu(spmm(h1@W2)); Z = spmm(h2@W3);
// A = sigmoid(Z @ Z^T).  Outputs: [A (12288x12288), Z (12288x16)] fp32, concat.
//
// Pipeline: memset(cnt) -> [csr_count || gemm1] -> csr_scan -> csr_scatter
//   -> spmm+relu+@W2 (fused) -> spmm+relu+@W3 (fused) -> spmm16 -> decode
// CSR scratch lives in the tail of A (decode overwrites it last).
//
// decode is LDS-staged (round-4's no-LDS variant was VMEM-issue-bound:
// 36 VMEM instr / 16 outputs = 367us). Here: 192 ds_read + 8 nt stores
// per 32 outputs -> HBM-write-bound (~96us floor).

constexpr int NN = 12288;   // nodes
constexpr int NE = 393216;  // edges
constexpr int KD = 1433;    // input dim

typedef float f32x4 __attribute__((ext_vector_type(4)));

// ---------------- fused: csr_count || gemm1 ----------------
__global__ __launch_bounds__(256) void k_count_gemm1(const int* __restrict__ er,
                                                     int* __restrict__ cnt,
                                                     const float* __restrict__ X,
                                                     const float* __restrict__ W,
                                                     float* __restrict__ out) {
    if (blockIdx.x < NE / 256) {
        int e = blockIdx.x * 256 + threadIdx.x;
        atomicAdd(&cnt[er[e]], 1);
        return;
    }
    int tid = (blockIdx.x - NE / 256) * 256 + threadIdx.x;
    int row = tid >> 5, col = tid & 31;
    const float* xr = X + (size_t)row * KD;
    float acc = 0.f;
    int head = (4 - (row & 3)) & 3;          // elements until 16B boundary
    for (int k = 0; k < head; ++k) acc += xr[k] * W[k * 32 + col];
    int nv = (KD - head) >> 2;               // float4 chunks
    const f32x4* x4 = (const f32x4*)(xr + head);
#pragma unroll 2
    for (int q = 0; q < nv; ++q) {
        f32x4 a = x4[q];
        int k = head + q * 4;
        acc += a[0] * W[(k + 0) * 32 + col];
        acc += a[1] * W[(k + 1) * 32 + col];
        acc += a[2] * W[(k + 2) * 32 + col];
        acc += a[3] * W[(k + 3) * 32 + col];
    }
    for (int k = head + nv * 4; k < KD; ++k) acc += xr[k] * W[k * 32 + col];
    out[(size_t)row * 32 + col] = acc;
}

// ---------------- CSR scan: one block, 1024 threads, 12 rows each ----------------
__global__ __launch_bounds__(1024) void csr_scan(const int* __restrict__ cnt,
                                                 int* __restrict__ ptr,
                                                 int* __restrict__ pos) {
    __shared__ int s[1024];
    int t = threadIdx.x;
    int base = t * 12;
    int loc[12];
    int sum = 0;
#pragma unroll
    for (int i = 0; i < 12; ++i) { loc[i] = sum; sum += cnt[base + i]; }
    s[t] = sum;
    __syncthreads();
    for (int off = 1; off < 1024; off <<= 1) {
        int v = (t >= off) ? s[t - off] : 0;
        __syncthreads();
        s[t] += v;
        __syncthreads();
    }
    int excl = (t == 0) ? 0 : s[t - 1];
#pragma unroll
    for (int i = 0; i < 12; ++i) {
        ptr[base + i] = excl + loc[i];
        pos[base + i] = excl + loc[i];
    }
    if (t == 0) ptr[NN] = NE;
}

__global__ __launch_bounds__(256) void csr_scatter(const float* __restrict__ ev,
                                                   const int* __restrict__ er,
                                                   const int* __restrict__ ec,
                                                   int* __restrict__ pos,
                                                   int* __restrict__ ecol,
                                                   float* __restrict__ eval) {
    int e = blockIdx.x * 256 + threadIdx.x;
    int r = er[e];
    int p = atomicAdd(&pos[r], 1);
    ecol[p] = ec[e];
    eval[p] = ev[e];
}

// ---------------- fused SpMM + relu + dense GEMM ----------------
template <int CO>
__global__ __launch_bounds__(256) void spmm_gemm(const float* __restrict__ in,
                                                 const float* __restrict__ Wm,
                                                 float* __restrict__ out,
                                                 const int* __restrict__ ptr,
                                                 const int* __restrict__ ecol,
                                                 const float* __restrict__ eval) {
    int tid = blockIdx.x * 256 + threadIdx.x;
    int r = tid >> 5, c = tid & 31;
    int lane = threadIdx.x & 63;
    int co = c & (CO - 1);
    float wcol[32];
#pragma unroll
    for (int k = 0; k < 32; ++k) wcol[k] = Wm[k * CO + co];
    int b = ptr[r], e = ptr[r + 1];
    float acc = 0.f;
#pragma unroll 2
    for (int i = b; i < e; ++i)
        acc += eval[i] * in[(size_t)ecol[i] * 32 + c];
    float h = fmaxf(acc, 0.f);
    float o = 0.f;
#pragma unroll
    for (int k = 0; k < 32; ++k) {
        float hk = __shfl(h, (lane & 32) + k);
        o += hk * wcol[k];
    }
    if (c < CO) out[(size_t)r * CO + co] = o;
}

// ---------------- plain SpMM gather, width 16 (final Z) ----------------
__global__ __launch_bounds__(256) void spmm16(const float* __restrict__ in,
                                              float* __restrict__ out,
                                              const int* __restrict__ ptr,
                                              const int* __restrict__ ecol,
                                              const float* __restrict__ eval) {
    int tid = blockIdx.x * 256 + threadIdx.x;
    int r = tid >> 4, c = tid & 15;
    int b = ptr[r], e = ptr[r + 1];
    float acc = 0.f;
#pragma unroll 2
    for (int i = b; i < e; ++i)
        acc += eval[i] * in[(size_t)ecol[i] * 16 + c];
    out[(size_t)r * 16 + c] = acc;
}

// ---------------- decode: A[i,j] = sigmoid(dot16(Z[i], Z[j])) ----------------
// 128(i) x 64(j) tile / 256 threads. Thread: 8 rows x 4 cols = 32 outputs,
// zj[4][16] in regs, zi[16] reloaded per row from LDS (broadcast reads,
// stride-17 rows -> conflict-free). 8 nontemporal float4 stores per thread.
__global__ __launch_bounds__(256) void decode(const float* __restrict__ Z,
                                              float* __restrict__ A) {
    __shared__ float zr[128][17];
    __shared__ float zc[64][17];
    int bi = blockIdx.y, bj = blockIdx.x;
    int tid = threadIdx.x;
    for (int i = tid; i < 128 * 16; i += 256) zr[i >> 4][i & 15] = Z[(size_t)bi * 2048 + i];
    for (int i = tid; i < 64 * 16; i += 256)  zc[i >> 4][i & 15] = Z[(size_t)bj * 1024 + i];
    __syncthreads();
    int tx = tid & 15;   // col group: 4 cols at bj*64 + tx*4
    int ty = tid >> 4;   // row group: 8 rows at bi*128 + ty*8
    float zj[4][16];
#pragma unroll
    for (int jj = 0; jj < 4; ++jj)
#pragma unroll
        for (int k = 0; k < 16; ++k) zj[jj][k] = zc[tx * 4 + jj][k];
#pragma unroll
    for (int r = 0; r < 8; ++r) {
        int i = ty * 8 + r;
        float zi[16];
#pragma unroll
        for (int k = 0; k < 16; ++k) zi[k] = zr[i][k];
        f32x4 o;
#pragma unroll
        for (int jj = 0; jj < 4; ++jj) {
            float dot = 0.f;
#pragma unroll
            for (int k = 0; k < 16; ++k) dot += zi[k] * zj[jj][k];
            float e = __expf(-dot);
            o[jj] = __fdividef(1.0f, 1.0f + e);
        }
        f32x4* dst = (f32x4*)&A[((size_t)bi * 128 + i) * NN + bj * 64 + tx * 4];
        __builtin_nontemporal_store(o, dst);
    }
}

extern "C" void kernel_launch(void* const* d_in, const int* in_sizes, int n_in,
                              void* d_out, int out_size, void* d_ws, size_t ws_size,
                              hipStream_t stream) {
    const float* X  = (const float*)d_in[0];
    const float* W1 = (const float*)d_in[1];
    const float* W2 = (const float*)d_in[2];
    const float* W3 = (const float*)d_in[3];
    const float* ev = (const float*)d_in[4];
    const int*   er = (const int*)d_in[5];
    const int*   ec = (const int*)d_in[6];

    float* A = (float*)d_out;                 // [NN, NN]
    float* Z = A + (size_t)NN * NN;           // [NN, 16]

    float* t1 = (float*)d_ws;                 // [NN, 32]  X@W1
    float* t2 = t1 + (size_t)NN * 32;         // [NN, 32]  relu(spmm(t1))@W2
    float* t3 = t2 + (size_t)NN * 32;         // [NN, 16]  relu(spmm(t2))@W3

    // CSR scratch in the tail of A (decode overwrites it last). ~3.3MB at
    // 560MB offset; A is 604MB.
    int*   cnt  = (int*)(A + (size_t)140000000);
    int*   ptr  = cnt + NN;          // NN+1
    int*   pos  = ptr + NN + 1;      // NN
    int*   ecol = pos + NN;          // NE
    float* eval = (float*)(ecol + NE);  // NE

    (void)hipMemsetAsync(cnt, 0, NN * sizeof(int), stream);

    // count || gemm1 (independent, fused into one dispatch)
    k_count_gemm1<<<NE / 256 + NN * 32 / 256, 256, 0, stream>>>(er, cnt, X, W1, t1);
    csr_scan<<<1, 1024, 0, stream>>>(cnt, ptr, pos);
    csr_scatter<<<NE / 256, 256, 0, stream>>>(ev, er, ec, pos, ecol, eval);

    // t2 = relu(spmm(t1)) @ W2
    spmm_gemm<32><<<NN * 32 / 256, 256, 0, stream>>>(t1, W2, t2, ptr, ecol, eval);
    // t3 = relu(spmm(t2)) @ W3
    spmm_gemm<16><<<NN * 32 / 256, 256, 0, stream>>>(t2, W3, t3, ptr, ecol, eval);
    // Z = spmm(t3)
    spmm16<<<NN * 16 / 256, 256, 0, stream>>>(t3, Z, ptr, ecol, eval);

    // A = sigmoid(Z @ Z^T)
    dim3 g(NN / 64, NN / 128);
    decode<<<g, 256, 0, stream>>>(Z, A);
}

// Round 6
// 346.633 us; speedup vs baseline: 1.7472x; 1.1714x over previous
//
#include <hip/hip_runtime.h>

// GAE: h1 = relu(spmm(X@W1)); h2 = relu(spmm(h1@W2)); Z = spmm(h2@W3);
// A = sigmoid(Z @ Z^T).  Outputs: [A (12288x12288), Z (12288x16)] fp32, concat.
//
// Pipeline: memset(cnt) -> [gemm1 || csr_count] -> csr_scan -> csr_scatter
//   -> spmm+relu+@W2 -> spmm+relu+@W3 -> spmm16 -> decode
// CSR scratch lives in the tail of A (decode overwrites it last).

constexpr int NN = 12288;   // nodes
constexpr int NE = 393216;  // edges
constexpr int KD = 1433;    // input dim

typedef float f32x4 __attribute__((ext_vector_type(4)));

// ---------------- fused: gemm1 (X@W1, LDS-tiled W) || csr_count ----------------
// gemm1: blocks [0,192): 64 rows each. W k-tiled (KT=256 -> 32KB LDS).
// thread: 4 cols (c4), 2 rows (rs, rs+32: same 16B phase -> shared W reads).
// Inner: 2 global f32x4 (X) + 4 ds_read_b128 (W) per 32 FMAs.
constexpr int KT = 256;
constexpr int G1B = NN / 64;  // 192 gemm blocks

__global__ __launch_bounds__(256) void k_count_gemm1(const int* __restrict__ er,
                                                     int* __restrict__ cnt,
                                                     const float* __restrict__ X,
                                                     const float* __restrict__ W,
                                                     float* __restrict__ out) {
    if (blockIdx.x >= G1B) {
        int e = (blockIdx.x - G1B) * 256 + threadIdx.x;
        atomicAdd(&cnt[er[e]], 1);
        return;
    }
    __shared__ float ws[KT * 32];
    int tid = threadIdx.x;
    int c4 = (tid & 7) * 4;
    int rs = tid >> 3;
    int r0 = blockIdx.x * 64 + rs;
    int r1 = r0 + 32;
    const float* x0 = X + (size_t)r0 * KD;
    const float* x1 = X + (size_t)r1 * KD;
    f32x4 acc0 = {0.f, 0.f, 0.f, 0.f};
    f32x4 acc1 = {0.f, 0.f, 0.f, 0.f};
    int phase = r0 & 3;                 // (r*KD + k0) % 4, KD%4==1, k0%4==0
    int h = (4 - phase) & 3;            // scalar head to reach 16B alignment

    for (int k0 = 0; k0 < KD; k0 += KT) {
        int kt = min(KT, KD - k0);
        __syncthreads();
        int n4 = (kt * 32) >> 2;
        for (int q = tid; q < n4; q += 256)
            *(f32x4*)(ws + q * 4) = *(const f32x4*)(W + (size_t)k0 * 32 + q * 4);
        __syncthreads();

        // scalar head (<=3)
        for (int kk = 0; kk < h; ++kk) {
            float a0 = x0[k0 + kk], a1 = x1[k0 + kk];
            const float* wr = ws + kk * 32 + c4;
#pragma unroll
            for (int j = 0; j < 4; ++j) { acc0[j] += a0 * wr[j]; acc1[j] += a1 * wr[j]; }
        }
        // vector body
        int nv = (kt - h) >> 2;
        const f32x4* p0 = (const f32x4*)(x0 + k0 + h);
        const f32x4* p1 = (const f32x4*)(x1 + k0 + h);
#pragma unroll 4
        for (int q = 0; q < nv; ++q) {
            f32x4 a0 = p0[q], a1 = p1[q];
            int kb = h + q * 4;
#pragma unroll
            for (int m = 0; m < 4; ++m) {
                f32x4 w4 = *(const f32x4*)(ws + (kb + m) * 32 + c4);
#pragma unroll
                for (int j = 0; j < 4; ++j) { acc0[j] += a0[m] * w4[j]; acc1[j] += a1[m] * w4[j]; }
            }
        }
        // scalar tail (<=3)
        for (int kk = h + nv * 4; kk < kt; ++kk) {
            float a0 = x0[k0 + kk], a1 = x1[k0 + kk];
            const float* wr = ws + kk * 32 + c4;
#pragma unroll
            for (int j = 0; j < 4; ++j) { acc0[j] += a0 * wr[j]; acc1[j] += a1 * wr[j]; }
        }
    }
    *(f32x4*)(out + (size_t)r0 * 32 + c4) = acc0;
    *(f32x4*)(out + (size_t)r1 * 32 + c4) = acc1;
}

// ---------------- CSR scan: one block, 1024 threads, 12 rows each ----------------
__global__ __launch_bounds__(1024) void csr_scan(const int* __restrict__ cnt,
                                                 int* __restrict__ ptr,
                                                 int* __restrict__ pos) {
    __shared__ int s[1024];
    int t = threadIdx.x;
    int base = t * 12;
    int loc[12];
    int sum = 0;
#pragma unroll
    for (int i = 0; i < 12; ++i) { loc[i] = sum; sum += cnt[base + i]; }
    s[t] = sum;
    __syncthreads();
    for (int off = 1; off < 1024; off <<= 1) {
        int v = (t >= off) ? s[t - off] : 0;
        __syncthreads();
        s[t] += v;
        __syncthreads();
    }
    int excl = (t == 0) ? 0 : s[t - 1];
#pragma unroll
    for (int i = 0; i < 12; ++i) {
        ptr[base + i] = excl + loc[i];
        pos[base + i] = excl + loc[i];
    }
    if (t == 0) ptr[NN] = NE;
}

__global__ __launch_bounds__(256) void csr_scatter(const float* __restrict__ ev,
                                                   const int* __restrict__ er,
                                                   const int* __restrict__ ec,
                                                   int* __restrict__ pos,
                                                   int* __restrict__ ecol,
                                                   float* __restrict__ eval) {
    int e = blockIdx.x * 256 + threadIdx.x;
    int r = er[e];
    int p = atomicAdd(&pos[r], 1);
    ecol[p] = ec[e];
    eval[p] = ev[e];
}

// ---------------- fused SpMM + relu + dense GEMM ----------------
template <int CO>
__global__ __launch_bounds__(256) void spmm_gemm(const float* __restrict__ in,
                                                 const float* __restrict__ Wm,
                                                 float* __restrict__ out,
                                                 const int* __restrict__ ptr,
                                                 const int* __restrict__ ecol,
                                                 const float* __restrict__ eval) {
    int tid = blockIdx.x * 256 + threadIdx.x;
    int r = tid >> 5, c = tid & 31;
    int lane = threadIdx.x & 63;
    int co = c & (CO - 1);
    float wcol[32];
#pragma unroll
    for (int k = 0; k < 32; ++k) wcol[k] = Wm[k * CO + co];
    int b = ptr[r], e = ptr[r + 1];
    float acc = 0.f;
#pragma unroll 2
    for (int i = b; i < e; ++i)
        acc += eval[i] * in[(size_t)ecol[i] * 32 + c];
    float h = fmaxf(acc, 0.f);
    float o = 0.f;
#pragma unroll
    for (int k = 0; k < 32; ++k) {
        float hk = __shfl(h, (lane & 32) + k);
        o += hk * wcol[k];
    }
    if (c < CO) out[(size_t)r * CO + co] = o;
}

// ---------------- plain SpMM gather, width 16 (final Z) ----------------
__global__ __launch_bounds__(256) void spmm16(const float* __restrict__ in,
                                              float* __restrict__ out,
                                              const int* __restrict__ ptr,
                                              const int* __restrict__ ecol,
                                              const float* __restrict__ eval) {
    int tid = blockIdx.x * 256 + threadIdx.x;
    int r = tid >> 4, c = tid & 15;
    int b = ptr[r], e = ptr[r + 1];
    float acc = 0.f;
#pragma unroll 2
    for (int i = b; i < e; ++i)
        acc += eval[i] * in[(size_t)ecol[i] * 16 + c];
    out[(size_t)r * 16 + c] = acc;
}

// ---------------- decode: A[i,j] = sigmoid(dot16(Z[i], Z[j])) ----------------
// 128x128 tile / 512 threads. Thread: 8 rows x 4 cols. Halves Z re-fetch per
// byte written vs 128x64 (write stream evicts Z from L2 -> refetch matters).
__global__ __launch_bounds__(512) void decode(const float* __restrict__ Z,
                                              float* __restrict__ A) {
    __shared__ float zr[128][17];
    __shared__ float zc[128][17];
    int bi = blockIdx.y, bj = blockIdx.x;
    int tid = threadIdx.x;
    for (int i = tid; i < 128 * 16; i += 512) {
        zr[i >> 4][i & 15] = Z[(size_t)bi * 2048 + i];
        zc[i >> 4][i & 15] = Z[(size_t)bj * 2048 + i];
    }
    __syncthreads();
    int tx = tid & 31;   // col group: 4 cols at bj*128 + tx*4
    int ty = tid >> 5;   // row group: 8 rows at bi*128 + ty*8
    float zj[4][16];
#pragma unroll
    for (int jj = 0; jj < 4; ++jj)
#pragma unroll
        for (int k = 0; k < 16; ++k) zj[jj][k] = zc[tx * 4 + jj][k];
#pragma unroll
    for (int r = 0; r < 8; ++r) {
        int i = ty * 8 + r;
        float zi[16];
#pragma unroll
        for (int k = 0; k < 16; ++k) zi[k] = zr[i][k];
        f32x4 o;
#pragma unroll
        for (int jj = 0; jj < 4; ++jj) {
            float dot = 0.f;
#pragma unroll
            for (int k = 0; k < 16; ++k) dot += zi[k] * zj[jj][k];
            float e = __expf(-dot);
            o[jj] = __fdividef(1.0f, 1.0f + e);
        }
        f32x4* dst = (f32x4*)&A[((size_t)bi * 128 + i) * NN + bj * 128 + tx * 4];
        __builtin_nontemporal_store(o, dst);
    }
}

extern "C" void kernel_launch(void* const* d_in, const int* in_sizes, int n_in,
                              void* d_out, int out_size, void* d_ws, size_t ws_size,
                              hipStream_t stream) {
    const float* X  = (const float*)d_in[0];
    const float* W1 = (const float*)d_in[1];
    const float* W2 = (const float*)d_in[2];
    const float* W3 = (const float*)d_in[3];
    const float* ev = (const float*)d_in[4];
    const int*   er = (const int*)d_in[5];
    const int*   ec = (const int*)d_in[6];

    float* A = (float*)d_out;                 // [NN, NN]
    float* Z = A + (size_t)NN * NN;           // [NN, 16]

    float* t1 = (float*)d_ws;                 // [NN, 32]  X@W1
    float* t2 = t1 + (size_t)NN * 32;         // [NN, 32]  relu(spmm(t1))@W2
    float* t3 = t2 + (size_t)NN * 32;         // [NN, 16]  relu(spmm(t2))@W3

    // CSR scratch in the tail of A (decode overwrites it last). ~3.3MB at
    // 560MB offset; A is 604MB.
    int*   cnt  = (int*)(A + (size_t)140000000);
    int*   ptr  = cnt + NN;          // NN+1
    int*   pos  = ptr + NN + 1;      // NN
    int*   ecol = pos + NN;          // NE
    float* eval = (float*)(ecol + NE);  // NE

    (void)hipMemsetAsync(cnt, 0, NN * sizeof(int), stream);

    // gemm1 (blocks 0..191) || count (blocks 192..1727)
    k_count_gemm1<<<G1B + NE / 256, 256, 0, stream>>>(er, cnt, X, W1, t1);
    csr_scan<<<1, 1024, 0, stream>>>(cnt, ptr, pos);
    csr_scatter<<<NE / 256, 256, 0, stream>>>(ev, er, ec, pos, ecol, eval);

    // t2 = relu(spmm(t1)) @ W2
    spmm_gemm<32><<<NN * 32 / 256, 256, 0, stream>>>(t1, W2, t2, ptr, ecol, eval);
    // t3 = relu(spmm(t2)) @ W3
    spmm_gemm<16><<<NN * 32 / 256, 256, 0, stream>>>(t2, W3, t3, ptr, ecol, eval);
    // Z = spmm(t3)
    spmm16<<<NN * 16 / 256, 256, 0, stream>>>(t3, Z, ptr, ecol, eval);

    // A = sigmoid(Z @ Z^T)
    dim3 g(NN / 128, NN / 128);
    decode<<<g, 512, 0, stream>>>(Z, A);
}

// Round 7
// 309.712 us; speedup vs baseline: 1.9555x; 1.1192x over previous
//
#include <hip/hip_runtime.h>

// GAE: h1 = relu(spmm(X@W1)); h2 = relu(spmm(h1@W2)); Z = spmm(h2@W3);
// A = sigmoid(Z @ Z^T).  Outputs: [A (12288x12288), Z (12288x16)] fp32, concat.
//
// Pipeline: memset(cnt) -> [gemm1 || csr_count] -> csr_scan -> csr_scatter
//   -> spmm+relu+@W2 -> spmm+relu+@W3 -> spmm16(+bf16 Z) -> decode_mfma
// CSR scratch lives in the tail of A (decode overwrites it last).
// Zb (bf16 copy of Z) lives in t1, which is dead by spmm16 time.

constexpr int NN = 12288;   // nodes
constexpr int NE = 393216;  // edges
constexpr int KD = 1433;    // input dim

typedef float f32x4 __attribute__((ext_vector_type(4)));
typedef float f32x16 __attribute__((ext_vector_type(16)));
typedef short shortx8 __attribute__((ext_vector_type(8)));

// ---------------- fused: gemm1 (X@W1, LDS-tiled W) || csr_count ----------------
constexpr int KT = 256;
constexpr int G1B = NN / 64;  // 192 gemm blocks

__global__ __launch_bounds__(256) void k_count_gemm1(const int* __restrict__ er,
                                                     int* __restrict__ cnt,
                                                     const float* __restrict__ X,
                                                     const float* __restrict__ W,
                                                     float* __restrict__ out) {
    if (blockIdx.x >= G1B) {
        int e = (blockIdx.x - G1B) * 256 + threadIdx.x;
        atomicAdd(&cnt[er[e]], 1);
        return;
    }
    __shared__ float ws[KT * 32];
    int tid = threadIdx.x;
    int c4 = (tid & 7) * 4;
    int rs = tid >> 3;
    int r0 = blockIdx.x * 64 + rs;
    int r1 = r0 + 32;
    const float* x0 = X + (size_t)r0 * KD;
    const float* x1 = X + (size_t)r1 * KD;
    f32x4 acc0 = {0.f, 0.f, 0.f, 0.f};
    f32x4 acc1 = {0.f, 0.f, 0.f, 0.f};
    int phase = r0 & 3;
    int h = (4 - phase) & 3;

    for (int k0 = 0; k0 < KD; k0 += KT) {
        int kt = min(KT, KD - k0);
        __syncthreads();
        int n4 = (kt * 32) >> 2;
        for (int q = tid; q < n4; q += 256)
            *(f32x4*)(ws + q * 4) = *(const f32x4*)(W + (size_t)k0 * 32 + q * 4);
        __syncthreads();

        for (int kk = 0; kk < h; ++kk) {
            float a0 = x0[k0 + kk], a1 = x1[k0 + kk];
            const float* wr = ws + kk * 32 + c4;
#pragma unroll
            for (int j = 0; j < 4; ++j) { acc0[j] += a0 * wr[j]; acc1[j] += a1 * wr[j]; }
        }
        int nv = (kt - h) >> 2;
        const f32x4* p0 = (const f32x4*)(x0 + k0 + h);
        const f32x4* p1 = (const f32x4*)(x1 + k0 + h);
#pragma unroll 4
        for (int q = 0; q < nv; ++q) {
            f32x4 a0 = p0[q], a1 = p1[q];
            int kb = h + q * 4;
#pragma unroll
            for (int m = 0; m < 4; ++m) {
                f32x4 w4 = *(const f32x4*)(ws + (kb + m) * 32 + c4);
#pragma unroll
                for (int j = 0; j < 4; ++j) { acc0[j] += a0[m] * w4[j]; acc1[j] += a1[m] * w4[j]; }
            }
        }
        for (int kk = h + nv * 4; kk < kt; ++kk) {
            float a0 = x0[k0 + kk], a1 = x1[k0 + kk];
            const float* wr = ws + kk * 32 + c4;
#pragma unroll
            for (int j = 0; j < 4; ++j) { acc0[j] += a0 * wr[j]; acc1[j] += a1 * wr[j]; }
        }
    }
    *(f32x4*)(out + (size_t)r0 * 32 + c4) = acc0;
    *(f32x4*)(out + (size_t)r1 * 32 + c4) = acc1;
}

// ---------------- CSR scan ----------------
__global__ __launch_bounds__(1024) void csr_scan(const int* __restrict__ cnt,
                                                 int* __restrict__ ptr,
                                                 int* __restrict__ pos) {
    __shared__ int s[1024];
    int t = threadIdx.x;
    int base = t * 12;
    int loc[12];
    int sum = 0;
#pragma unroll
    for (int i = 0; i < 12; ++i) { loc[i] = sum; sum += cnt[base + i]; }
    s[t] = sum;
    __syncthreads();
    for (int off = 1; off < 1024; off <<= 1) {
        int v = (t >= off) ? s[t - off] : 0;
        __syncthreads();
        s[t] += v;
        __syncthreads();
    }
    int excl = (t == 0) ? 0 : s[t - 1];
#pragma unroll
    for (int i = 0; i < 12; ++i) {
        ptr[base + i] = excl + loc[i];
        pos[base + i] = excl + loc[i];
    }
    if (t == 0) ptr[NN] = NE;
}

__global__ __launch_bounds__(256) void csr_scatter(const float* __restrict__ ev,
                                                   const int* __restrict__ er,
                                                   const int* __restrict__ ec,
                                                   int* __restrict__ pos,
                                                   int* __restrict__ ecol,
                                                   float* __restrict__ eval) {
    int e = blockIdx.x * 256 + threadIdx.x;
    int r = er[e];
    int p = atomicAdd(&pos[r], 1);
    ecol[p] = ec[e];
    eval[p] = ev[e];
}

// ---------------- fused SpMM + relu + dense GEMM ----------------
template <int CO>
__global__ __launch_bounds__(256) void spmm_gemm(const float* __restrict__ in,
                                                 const float* __restrict__ Wm,
                                                 float* __restrict__ out,
                                                 const int* __restrict__ ptr,
                                                 const int* __restrict__ ecol,
                                                 const float* __restrict__ eval) {
    int tid = blockIdx.x * 256 + threadIdx.x;
    int r = tid >> 5, c = tid & 31;
    int lane = threadIdx.x & 63;
    int co = c & (CO - 1);
    float wcol[32];
#pragma unroll
    for (int k = 0; k < 32; ++k) wcol[k] = Wm[k * CO + co];
    int b = ptr[r], e = ptr[r + 1];
    float acc = 0.f;
#pragma unroll 2
    for (int i = b; i < e; ++i)
        acc += eval[i] * in[(size_t)ecol[i] * 32 + c];
    float h = fmaxf(acc, 0.f);
    float o = 0.f;
#pragma unroll
    for (int k = 0; k < 32; ++k) {
        float hk = __shfl(h, (lane & 32) + k);
        o += hk * wcol[k];
    }
    if (c < CO) out[(size_t)r * CO + co] = o;
}

// ---------------- SpMM width 16 -> Z (fp32) and Zb (bf16) ----------------
__global__ __launch_bounds__(256) void spmm16(const float* __restrict__ in,
                                              float* __restrict__ out,
                                              unsigned short* __restrict__ zb,
                                              const int* __restrict__ ptr,
                                              const int* __restrict__ ecol,
                                              const float* __restrict__ eval) {
    int tid = blockIdx.x * 256 + threadIdx.x;
    int r = tid >> 4, c = tid & 15;
    int b = ptr[r], e = ptr[r + 1];
    float acc = 0.f;
#pragma unroll 2
    for (int i = b; i < e; ++i)
        acc += eval[i] * in[(size_t)ecol[i] * 16 + c];
    out[(size_t)r * 16 + c] = acc;
    unsigned int bits = __float_as_uint(acc);
    zb[(size_t)r * 16 + c] = (unsigned short)((bits + 0x7FFFu + ((bits >> 16) & 1u)) >> 16);
}

// ---------------- decode via MFMA: A = sigmoid(Zb @ Zb^T) ----------------
// 128x128 tile / 4 waves; wave = 64x64 quadrant = 4x mfma_f32_32x32x16_bf16.
// Fragment loads straight from global Zb: lane l reads 16B at row (base+l&31),
// k-half (l>>5) -> the 64 lanes cover a contiguous permuted 1KB. No LDS.
// A-frag: row=l&31, k=(l>>5)*8+j.  B-frag: col=l&31, k=(l>>5)*8+j.
// D (m74-verified): col=l&31, row=(q&3)+8*(q>>2)+4*(l>>5), q=0..15.
__global__ __launch_bounds__(256) void decode_mfma(const unsigned short* __restrict__ Zb,
                                                   float* __restrict__ A) {
    int id = blockIdx.x;
    int f = (id & 7) * (9216 / 8) + (id >> 3);   // XCD swizzle (bijective: 9216%8==0)
    int bi = f / 96, bj = f % 96;
    int w = threadIdx.x >> 6;
    int l = threadIdx.x & 63;
    int R = bi * 128 + (w >> 1) * 64;
    int C = bj * 128 + (w & 1) * 64;
    int lr = l & 31, lh = l >> 5;

    shortx8 a0 = *(const shortx8*)(Zb + ((size_t)(R + lr) << 4) + lh * 8);
    shortx8 a1 = *(const shortx8*)(Zb + ((size_t)(R + 32 + lr) << 4) + lh * 8);
    shortx8 b0 = *(const shortx8*)(Zb + ((size_t)(C + lr) << 4) + lh * 8);
    shortx8 b1 = *(const shortx8*)(Zb + ((size_t)(C + 32 + lr) << 4) + lh * 8);

    f32x16 acc00 = {0.f}, acc01 = {0.f}, acc10 = {0.f}, acc11 = {0.f};
    acc00 = __builtin_amdgcn_mfma_f32_32x32x16_bf16(a0, b0, acc00, 0, 0, 0);
    acc01 = __builtin_amdgcn_mfma_f32_32x32x16_bf16(a0, b1, acc01, 0, 0, 0);
    acc10 = __builtin_amdgcn_mfma_f32_32x32x16_bf16(a1, b0, acc10, 0, 0, 0);
    acc11 = __builtin_amdgcn_mfma_f32_32x32x16_bf16(a1, b1, acc11, 0, 0, 0);

#pragma unroll
    for (int q = 0; q < 16; ++q) {
        int rf = (q & 3) + 8 * (q >> 2) + 4 * lh;
        float s00 = __fdividef(1.0f, 1.0f + __expf(-acc00[q]));
        float s01 = __fdividef(1.0f, 1.0f + __expf(-acc01[q]));
        float s10 = __fdividef(1.0f, 1.0f + __expf(-acc10[q]));
        float s11 = __fdividef(1.0f, 1.0f + __expf(-acc11[q]));
        __builtin_nontemporal_store(s00, &A[(size_t)(R + rf) * NN + C + lr]);
        __builtin_nontemporal_store(s01, &A[(size_t)(R + rf) * NN + C + 32 + lr]);
        __builtin_nontemporal_store(s10, &A[(size_t)(R + 32 + rf) * NN + C + lr]);
        __builtin_nontemporal_store(s11, &A[(size_t)(R + 32 + rf) * NN + C + 32 + lr]);
    }
}

extern "C" void kernel_launch(void* const* d_in, const int* in_sizes, int n_in,
                              void* d_out, int out_size, void* d_ws, size_t ws_size,
                              hipStream_t stream) {
    const float* X  = (const float*)d_in[0];
    const float* W1 = (const float*)d_in[1];
    const float* W2 = (const float*)d_in[2];
    const float* W3 = (const float*)d_in[3];
    const float* ev = (const float*)d_in[4];
    const int*   er = (const int*)d_in[5];
    const int*   ec = (const int*)d_in[6];

    float* A = (float*)d_out;                 // [NN, NN]
    float* Z = A + (size_t)NN * NN;           // [NN, 16]

    float* t1 = (float*)d_ws;                 // [NN, 32]  X@W1; later Zb (bf16)
    float* t2 = t1 + (size_t)NN * 32;         // [NN, 32]
    float* t3 = t2 + (size_t)NN * 32;         // [NN, 16]
    unsigned short* Zb = (unsigned short*)t1; // [NN, 16] bf16 (t1 dead by then)

    // CSR scratch in the tail of A (decode overwrites it last). ~3.3MB at
    // 560MB offset; A is 604MB.
    int*   cnt  = (int*)(A + (size_t)140000000);
    int*   ptr  = cnt + NN;          // NN+1
    int*   pos  = ptr + NN + 1;      // NN
    int*   ecol = pos + NN;          // NE
    float* eval = (float*)(ecol + NE);  // NE

    (void)hipMemsetAsync(cnt, 0, NN * sizeof(int), stream);

    // gemm1 (blocks 0..191) || count (blocks 192..1727)
    k_count_gemm1<<<G1B + NE / 256, 256, 0, stream>>>(er, cnt, X, W1, t1);
    csr_scan<<<1, 1024, 0, stream>>>(cnt, ptr, pos);
    csr_scatter<<<NE / 256, 256, 0, stream>>>(ev, er, ec, pos, ecol, eval);

    // t2 = relu(spmm(t1)) @ W2
    spmm_gemm<32><<<NN * 32 / 256, 256, 0, stream>>>(t1, W2, t2, ptr, ecol, eval);
    // t3 = relu(spmm(t2)) @ W3
    spmm_gemm<16><<<NN * 32 / 256, 256, 0, stream>>>(t2, W3, t3, ptr, ecol, eval);
    // Z = spmm(t3); Zb = bf16(Z) into t1 (dead)
    spmm16<<<NN * 16 / 256, 256, 0, stream>>>(t3, Z, Zb, ptr, ecol, eval);

    // A = sigmoid(Z @ Z^T) via MFMA
    decode_mfma<<<96 * 96, 256, 0, stream>>>(Zb, A);
}